// Round 1
// baseline (3124.010 us; speedup 1.0000x reference)
//
#include <hip/hip_runtime.h>
#include <stdint.h>

#define NU 200000
#define NM 100000
#define DIM 64

// ---------------------------------------------------------------------------
// Detect whether edge index arrays are int64 or int32.
// If int64 (little-endian), every odd 32-bit word (high half) is 0 since
// indices < 200000. If int32, odd words are real indices; P(2048 all zero)~0.
__global__ void detect_idx_kernel(const unsigned int* __restrict__ words,
                                  int* __restrict__ flag) {
    __shared__ int nz;
    if (threadIdx.x == 0) nz = 0;
    __syncthreads();
    for (int i = threadIdx.x; i < 2048; i += blockDim.x)
        if (words[2 * i + 1] != 0u) nz = 1;
    __syncthreads();
    if (threadIdx.x == 0) *flag = (nz == 0) ? 1 : 0;   // 1 => int64
}

__device__ __forceinline__ int load_idx(const void* __restrict__ p, int e, int is64) {
    if (is64) return (int)((const long long*)p)[e];
    return ((const int*)p)[e];
}

// ---------------------------------------------------------------------------
// Edge scatter: for each edge e, agg[sidx[e], :] += xg[gidx[e], :]
// One wave (64 lanes) handles one edge (lane = feature dim) -> coalesced
// 256B gather + 256B contiguous atomic adds.
__global__ void scatter_kernel(const float* __restrict__ xg,
                               const void* __restrict__ gidx,
                               const void* __restrict__ sidx,
                               const int* __restrict__ flag,
                               float* __restrict__ agg,
                               float* __restrict__ cnt,
                               int nE, int do_cnt) {
    const int is64 = *flag;
    const long long stride = (long long)gridDim.x * blockDim.x;
    const long long total = (long long)nE * 64;
    for (long long t = (long long)blockIdx.x * blockDim.x + threadIdx.x;
         t < total; t += stride) {
        int e = (int)(t >> 6);
        int d = (int)(t & 63);
        int g = load_idx(gidx, e, is64);
        int s = load_idx(sidx, e, is64);
        float v = xg[(size_t)g * DIM + d];
        atomicAdd(&agg[(size_t)s * DIM + d], v);
        if (do_cnt && d == 0) atomicAdd(&cnt[s], 1.0f);
    }
}

// ---------------------------------------------------------------------------
// Per-node: out[i,:] = opt_relu( (agg[i,:]/max(cnt,1)) @ Wl + bl + x[i,:] @ Wr )
// One wave per node; weights staged in LDS; input row broadcast via __shfl.
// Safe for in-place x == out (row read fully before row write, same wave).
template <int RELU>
__global__ void node_kernel(const float* __restrict__ agg,
                            const float* __restrict__ cnt,
                            const float* __restrict__ x,
                            const float* __restrict__ Wl,
                            const float* __restrict__ bl,
                            const float* __restrict__ Wr,
                            float* __restrict__ out, int n) {
    __shared__ float sW[2][DIM * DIM];
    for (int i = threadIdx.x; i < DIM * DIM; i += blockDim.x) {
        sW[0][i] = Wl[i];
        sW[1][i] = Wr[i];
    }
    __syncthreads();
    const int lane = threadIdx.x & 63;
    const int wib  = threadIdx.x >> 6;
    const int wpb  = blockDim.x >> 6;
    const float bias = bl[lane];
    for (int i = blockIdx.x * wpb + wib; i < n; i += gridDim.x * wpb) {
        float inv = 1.0f / fmaxf(cnt[i], 1.0f);
        float a  = agg[(size_t)i * DIM + lane] * inv;
        float xr = x[(size_t)i * DIM + lane];
        float acc = bias;
#pragma unroll 16
        for (int k = 0; k < DIM; ++k) {
            acc += __shfl(a, k)  * sW[0][k * DIM + lane];
            acc += __shfl(xr, k) * sW[1][k * DIM + lane];
        }
        if (RELU) acc = fmaxf(acc, 0.0f);
        out[(size_t)i * DIM + lane] = acc;
    }
}

// ---------------------------------------------------------------------------
extern "C" void kernel_launch(void* const* d_in, const int* in_sizes, int n_in,
                              void* d_out, int out_size, void* d_ws, size_t ws_size,
                              hipStream_t stream) {
    const float* x_user  = (const float*)d_in[0];
    const float* x_movie = (const float*)d_in[1];
    const void*  e_src   = d_in[2];
    const void*  e_dst   = d_in[3];
    const float* W1_um_l = (const float*)d_in[4];
    const float* W1_um_r = (const float*)d_in[5];
    const float* W1_mu_l = (const float*)d_in[6];
    const float* W1_mu_r = (const float*)d_in[7];
    const float* W2_um_l = (const float*)d_in[8];
    const float* W2_um_r = (const float*)d_in[9];
    const float* W2_mu_l = (const float*)d_in[10];
    const float* W2_mu_r = (const float*)d_in[11];
    const float* b1_um = (const float*)d_in[12];
    const float* b1_mu = (const float*)d_in[13];
    const float* b2_um = (const float*)d_in[14];
    const float* b2_mu = (const float*)d_in[15];
    const int nE = in_sizes[2];

    // workspace carve-up (256B aligned): flag, counts, two aggregate buffers
    char* ws = (char*)d_ws;
    size_t off = 0;
    auto carve = [&](size_t bytes) {
        void* p = ws + off;
        off += (bytes + 255) & ~(size_t)255;
        return p;
    };
    int*   flag  = (int*)  carve(4);
    float* cnt_u = (float*)carve((size_t)NU * 4);
    float* cnt_m = (float*)carve((size_t)NM * 4);
    float* agg_u = (float*)carve((size_t)NU * DIM * 4);
    float* agg_m = (float*)carve((size_t)NM * DIM * 4);

    // intermediates u1/m1 live in d_out (u2/m2 slots), overwritten in-place later
    float* u2 = (float*)d_out;                    // [NU,64]
    float* m2 = (float*)d_out + (size_t)NU * DIM; // [NM,64]
    float* u1 = u2;
    float* m1 = m2;

    hipMemsetAsync(cnt_u, 0, (size_t)NU * 4, stream);
    hipMemsetAsync(cnt_m, 0, (size_t)NM * 4, stream);
    hipMemsetAsync(agg_u, 0, (size_t)NU * DIM * 4, stream);
    hipMemsetAsync(agg_m, 0, (size_t)NM * DIM * 4, stream);

    detect_idx_kernel<<<1, 256, 0, stream>>>((const unsigned int*)e_src, flag);

    const int SCB = 8192;   // scatter blocks (grid-stride over nE*64)
    // layer 1 aggregation (+ degree counts, once)
    scatter_kernel<<<SCB, 256, 0, stream>>>(x_user,  e_src, e_dst, flag, agg_m, cnt_m, nE, 1);
    scatter_kernel<<<SCB, 256, 0, stream>>>(x_movie, e_dst, e_src, flag, agg_u, cnt_u, nE, 1);

    int nbm = (NM + 3) / 4; if (nbm > 16384) nbm = 16384;
    int nbu = (NU + 3) / 4; if (nbu > 16384) nbu = 16384;
    node_kernel<1><<<nbm, 256, 0, stream>>>(agg_m, cnt_m, x_movie, W1_um_l, b1_um, W1_um_r, m1, NM);
    node_kernel<1><<<nbu, 256, 0, stream>>>(agg_u, cnt_u, x_user,  W1_mu_l, b1_mu, W1_mu_r, u1, NU);

    // layer 2 aggregation
    hipMemsetAsync(agg_u, 0, (size_t)NU * DIM * 4, stream);
    hipMemsetAsync(agg_m, 0, (size_t)NM * DIM * 4, stream);
    scatter_kernel<<<SCB, 256, 0, stream>>>(u1, e_src, e_dst, flag, agg_m, nullptr, nE, 0);
    scatter_kernel<<<SCB, 256, 0, stream>>>(m1, e_dst, e_src, flag, agg_u, nullptr, nE, 0);

    // layer 2 node transform; m2 first (overwrites m1 after agg built),
    // then u2 (u1 still intact until here).
    node_kernel<0><<<nbm, 256, 0, stream>>>(agg_m, cnt_m, m1, W2_um_l, b2_um, W2_um_r, m2, NM);
    node_kernel<0><<<nbu, 256, 0, stream>>>(agg_u, cnt_u, u1, W2_mu_l, b2_mu, W2_mu_r, u2, NU);
}